// Round 5
// baseline (9927.303 us; speedup 1.0000x reference)
//
#include <hip/hip_runtime.h>
#include <hip/hip_bf16.h>
#include <hip/hip_cooperative_groups.h>
#include <cstddef>

namespace cg = cooperative_groups;

typedef short bf16x8 __attribute__((ext_vector_type(8)));
typedef float f32x4 __attribute__((ext_vector_type(4)));

#define T_STEPS 512
#define BATCH   64
#define DIM     1024   // I == H == 1024
#define BD      (BATCH*DIM)      // 65536
#define XB_ELEMS ((size_t)T_STEPS*BATCH*DIM)  // 33554432

__device__ __forceinline__ float sigmoidf_(float x) {
    return 1.f / (1.f + __expf(-x));
}
__device__ __forceinline__ float tanhf_(float x) {
    return 2.f / (1.f + __expf(-2.f * x)) - 1.f;
}
__device__ __forceinline__ unsigned short f2bf(float f) {
    union { float f; unsigned int u; } v; v.f = f;
    unsigned int u = v.u + 0x7fffu + ((v.u >> 16) & 1u);  // RNE
    return (unsigned short)(u >> 16);
}

// coherent (agent-scope, cache-bypassing) 8B primitives for h traffic
__device__ __forceinline__ unsigned long long coh_load8(const void* p) {
    return __hip_atomic_load((const unsigned long long*)p,
                             __ATOMIC_RELAXED, __HIP_MEMORY_SCOPE_AGENT);
}
__device__ __forceinline__ void coh_store8(void* p, unsigned long long v) {
    __hip_atomic_store((unsigned long long*)p, v,
                       __ATOMIC_RELAXED, __HIP_MEMORY_SCOPE_AGENT);
}

// Grid: 256 blocks x 256 threads. Blocks 0..127 -> layer 0, 128..255 -> layer 1.
__global__ void __launch_bounds__(256, 1)
lstm_fused(const float* __restrict__ x,
           const float* __restrict__ hx,
           const float* __restrict__ cx,
           const float* __restrict__ w_ih0, const float* __restrict__ w_hh0,
           const float* __restrict__ b_ih0, const float* __restrict__ b_hh0,
           const float* __restrict__ w_ih1, const float* __restrict__ w_hh1,
           const float* __restrict__ b_ih1, const float* __restrict__ b_hh1,
           float* __restrict__ out,
           unsigned short* __restrict__ ws)
{
    // ws layout (bf16 elems): xb[T][B][DIM], h0[4][BD], h1[2][BD], flags
    unsigned short* xb = ws;
    unsigned short* h0 = ws + XB_ELEMS;
    unsigned short* h1 = h0 + 4 * BD;
    unsigned* flag0 = (unsigned*)(h1 + 2 * BD);   // [128] packed, 512B
    unsigned* flag1 = flag0 + 128;                // [128] packed, 512B

    const int tid   = threadIdx.x;
    const int lane  = tid & 63;
    const int wave  = tid >> 6;
    const int bid   = blockIdx.x;
    const int layer = bid >> 7;
    const int ib    = bid & 127;
    const int hb    = ib * 8;          // first hidden unit owned by this block

    // B operand in MFMA fragment order: [g(2)][ntile(2)][kchunk(32)][lane(64)][8]
    __shared__ __align__(16) unsigned short wB[65536];     // 128 KB
    __shared__ __align__(16) unsigned short hstage[64][8]; // 1 KB repack tile

    // ---- stage weight slices into LDS (one-time), fragment layout ----
    {
        const float* wsrcI = layer ? w_ih1 : w_ih0;
        const float* wsrcH = layer ? w_hh1 : w_hh0;
        for (int idx = tid; idx < 8192; idx += 256) {   // 8192 fragments of 8
            int l  = idx & 63;
            int kc = (idx >> 6) & 31;
            int n  = (idx >> 11) & 1;
            int g  = idx >> 12;
            int c  = l & 15, kq = l >> 4;
            int gate = n * 2 + (c >> 3);                // 0:i 1:f 2:g 3:o
            const float* wm = g ? wsrcH : wsrcI;
            const float* src = wm + (size_t)(gate * DIM + hb + (c & 7)) * DIM + kc * 32 + kq * 8;
            float4 v0 = *(const float4*)(src);
            float4 v1 = *(const float4*)(src + 4);
            unsigned short o[8];
            o[0] = f2bf(v0.x); o[1] = f2bf(v0.y); o[2] = f2bf(v0.z); o[3] = f2bf(v0.w);
            o[4] = f2bf(v1.x); o[5] = f2bf(v1.y); o[6] = f2bf(v1.z); o[7] = f2bf(v1.w);
            *(bf16x8*)(&wB[(size_t)idx * 8]) = *(const bf16x8*)o;
        }
    }

    // ---- cast x to bf16 into ws (grid-stride) ----
    {
        const int nthr = 256 * gridDim.x;
        const int gtid = bid * 256 + tid;
        const float4* xv = (const float4*)x;
        const int n4 = (int)(XB_ELEMS / 4);
        for (int i = gtid; i < n4; i += nthr) {
            float4 v = xv[i];
            ushort4 o;
            o.x = f2bf(v.x); o.y = f2bf(v.y); o.z = f2bf(v.z); o.w = f2bf(v.w);
            *(ushort4*)(xb + (size_t)i * 4) = o;
        }
    }

    // ---- init h ring slots holding h[-1] (l0: slot 3 of 4; l1: slot 1 of 2) ----
    {
        unsigned short* hdst = layer ? (h1 + BD) : (h0 + 3 * BD);
        const float* hsrc = hx + (size_t)layer * BD;
        for (int e = tid; e < 512; e += 256) {
            int row = e >> 3, u = e & 7;
            hdst[row * DIM + hb + u] = f2bf(hsrc[row * DIM + hb + u]);
        }
    }

    // ---- zero own flag word (every launch; deterministic under graph replay) ----
    if (tid == 0) {
        unsigned* f = (layer ? flag1 : flag0) + ib;
        __hip_atomic_store(f, 0u, __ATOMIC_RELAXED, __HIP_MEMORY_SCOPE_AGENT);
    }

    const int col  = lane & 15;      // MFMA col within N-tile
    const int quad = lane >> 4;      // 0..3
    const bool lo  = col < 8;
    const int u    = lane & 7;       // hidden-unit offset for lo lanes

    // biases (per-lane, constant over time)
    const float* bi = layer ? b_ih1 : b_ih0;
    const float* bh = layer ? b_hh1 : b_hh0;
    const int r0 = (col < 8) ? (0 * DIM + hb + col) : (1 * DIM + hb + col - 8); // i|f
    const int r1 = (col < 8) ? (2 * DIM + hb + col) : (3 * DIM + hb + col - 8); // g|o
    const float bias0 = bi[r0] + bh[r0];
    const float bias1 = bi[r1] + bh[r1];

    // c-state in registers (lo lanes own 4 batch rows each)
    float creg[4];
    {
        const float* csrc = cx + (size_t)layer * BD;
        #pragma unroll
        for (int r = 0; r < 4; ++r) {
            int m = wave * 16 + quad * 4 + r;
            creg[r] = lo ? csrc[m * DIM + hb + u] : 0.f;
        }
    }

    cg::grid_group grid = cg::this_grid();
    __syncthreads();
    grid.sync();   // publishes xb, h init, zeroed flags (wbl2 + inv once)

    const int arow = wave * 16 + col;  // A-fragment row (batch index)

    // plain-load GEMM (xb path: L2-cacheable, stays warm — no invalidates ever)
    auto do_gemm_plain = [&](const unsigned short* Ap, int g, f32x4& a0v, f32x4& a1v) {
        const unsigned short* Abase = Ap + (size_t)arow * DIM + quad * 8;
        const unsigned short* B0 = &wB[(size_t)((g * 2 + 0) * 32) * 512 + lane * 8];
        const unsigned short* B1 = &wB[(size_t)((g * 2 + 1) * 32) * 512 + lane * 8];
        #pragma unroll 8
        for (int kc = 0; kc < 32; ++kc) {
            bf16x8 a  = *(const bf16x8*)(Abase + kc * 32);
            bf16x8 b0 = *(const bf16x8*)(B0 + (size_t)kc * 512);
            bf16x8 b1 = *(const bf16x8*)(B1 + (size_t)kc * 512);
            a0v = __builtin_amdgcn_mfma_f32_16x16x32_bf16(a, b0, a0v, 0, 0, 0);
            a1v = __builtin_amdgcn_mfma_f32_16x16x32_bf16(a, b1, a1v, 0, 0, 0);
        }
    };

    // coherent-load GEMM, 8-deep register prefetch (16 loads in flight/lane)
    auto do_gemm_coh = [&](const unsigned short* Ap, int g, f32x4& a0v, f32x4& a1v) {
        const unsigned short* Abase = Ap + (size_t)arow * DIM + quad * 8;
        const unsigned short* B0 = &wB[(size_t)((g * 2 + 0) * 32) * 512 + lane * 8];
        const unsigned short* B1 = &wB[(size_t)((g * 2 + 1) * 32) * 512 + lane * 8];
        union U { bf16x8 v; unsigned long long q[2]; };
        U pre[8];
        #pragma unroll
        for (int i = 0; i < 8; ++i) {
            pre[i].q[0] = coh_load8(Abase + i * 32);
            pre[i].q[1] = coh_load8(Abase + i * 32 + 4);
        }
        #pragma unroll
        for (int kc = 0; kc < 32; ++kc) {
            U cur = pre[kc & 7];
            if (kc < 24) {
                pre[kc & 7].q[0] = coh_load8(Abase + (kc + 8) * 32);
                pre[kc & 7].q[1] = coh_load8(Abase + (kc + 8) * 32 + 4);
            }
            bf16x8 b0 = *(const bf16x8*)(B0 + (size_t)kc * 512);
            bf16x8 b1 = *(const bf16x8*)(B1 + (size_t)kc * 512);
            a0v = __builtin_amdgcn_mfma_f32_16x16x32_bf16(cur.v, b0, a0v, 0, 0, 0);
            a1v = __builtin_amdgcn_mfma_f32_16x16x32_bf16(cur.v, b1, a1v, 0, 0, 0);
        }
    };

    // early-probe / late-finish distributed barrier (packed coalesced flags)
    auto probe = [&](const unsigned* flags) -> unsigned {
        return (tid < 128)
            ? __hip_atomic_load(flags + tid, __ATOMIC_RELAXED, __HIP_MEMORY_SCOPE_AGENT)
            : 0xFFFFFFFFu;
    };
    auto finish_wait = [&](const unsigned* flags, unsigned target, unsigned seen) {
        if (tid < 128 && seen < target) {
            while (__hip_atomic_load(flags + tid, __ATOMIC_RELAXED,
                                     __HIP_MEMORY_SCOPE_AGENT) < target)
                __builtin_amdgcn_s_sleep(12);   // ~0.3 us backoff: no poll storm
        }
        __syncthreads();
    };

    unsigned* myflag = (layer ? flag1 : flag0) + ib;

    for (int t = 0; t < T_STEPS; ++t) {
        f32x4 acc0 = {0.f, 0.f, 0.f, 0.f};
        f32x4 acc1 = {0.f, 0.f, 0.f, 0.f};
        unsigned pf0, pf1;

        if (!layer) {
            pf0 = probe(flag0);
            pf1 = probe(flag1);
            // input GEMM on static xb[t] — covers the flag probes
            do_gemm_plain(xb + (size_t)t * BD, 0, acc0, acc1);
            finish_wait(flag0, (unsigned)t, pf0);          // peers' h0[t-1] ready
            do_gemm_coh(h0 + (size_t)((t - 1) & 3) * BD, 1, acc0, acc1);
            if (t >= 4) finish_wait(flag1, (unsigned)(t - 3), pf1); // slot t&3 free
        } else {
            pf1 = probe(flag1);
            pf0 = probe(flag0);
            finish_wait(flag1, (unsigned)t, pf1);          // peers' h1[t-1] ready
            do_gemm_coh(h1 + (size_t)((t - 1) & 1) * BD, 1, acc0, acc1);
            finish_wait(flag0, (unsigned)(t + 1), pf0);    // layer0's h0[t] ready
            do_gemm_coh(h0 + (size_t)(t & 3) * BD, 0, acc0, acc1);
        }

        unsigned short* hout = layer ? (h1 + (size_t)(t & 1) * BD)
                                     : (h0 + (size_t)(t & 3) * BD);
        float hreg[4];
        #pragma unroll
        for (int r = 0; r < 4; ++r) {
            float pre0 = acc0[r] + bias0;          // i (lo) | f (hi)
            float pre1 = acc1[r] + bias1;          // g (lo) | o (hi)
            float alt0 = __shfl_xor(pre0, 8);
            float alt1 = __shfl_xor(pre1, 8);
            if (lo) {
                float ig = sigmoidf_(pre0);
                float fg = sigmoidf_(alt0);
                float gg = tanhf_(pre1);
                float og = sigmoidf_(alt1);
                float c  = fg * creg[r] + ig * gg;
                creg[r]  = c;
                float h  = og * tanhf_(c);
                hreg[r]  = h;
                int m = wave * 16 + quad * 4 + r;
                hstage[m][u] = f2bf(h);
            }
        }
        __syncthreads();                 // hstage complete
        if (tid < 64) {                  // 16B/row contiguous write-through
            const unsigned long long* src = (const unsigned long long*)&hstage[tid][0];
            unsigned long long v0 = src[0], v1 = src[1];
            void* dst = hout + (size_t)tid * DIM + hb;
            coh_store8(dst, v0);
            coh_store8((char*)dst + 8, v1);
        }
        asm volatile("s_waitcnt vmcnt(0)" ::: "memory");   // h at L3
        __syncthreads();                                   // all waves drained
        if (tid == 0)
            __hip_atomic_store(myflag, (unsigned)(t + 1),
                               __ATOMIC_RELAXED, __HIP_MEMORY_SCOPE_AGENT);

        // non-critical-path output stores (after flag publish)
        if (lo) {
            #pragma unroll
            for (int r = 0; r < 4; ++r) {
                int m = wave * 16 + quad * 4 + r;
                if (layer) {
                    out[(size_t)t * BD + m * DIM + hb + u] = hreg[r];
                    if (t == T_STEPS - 1) {
                        out[(size_t)T_STEPS * BD + 1 * BD + m * DIM + hb + u] = hreg[r];  // hn[1]
                        out[(size_t)T_STEPS * BD + 3 * BD + m * DIM + hb + u] = creg[r];  // cn[1]
                    }
                } else if (t == T_STEPS - 1) {
                    out[(size_t)T_STEPS * BD + 0 * BD + m * DIM + hb + u] = hreg[r];      // hn[0]
                    out[(size_t)T_STEPS * BD + 2 * BD + m * DIM + hb + u] = creg[r];      // cn[0]
                }
            }
        }
    }
}

extern "C" void kernel_launch(void* const* d_in, const int* in_sizes, int n_in,
                              void* d_out, int out_size, void* d_ws, size_t ws_size,
                              hipStream_t stream) {
    const float* x     = (const float*)d_in[0];
    const float* hx    = (const float*)d_in[1];
    const float* cx    = (const float*)d_in[2];
    const float* w_ih0 = (const float*)d_in[3];
    const float* w_hh0 = (const float*)d_in[4];
    const float* b_ih0 = (const float*)d_in[5];
    const float* b_hh0 = (const float*)d_in[6];
    const float* w_ih1 = (const float*)d_in[7];
    const float* w_hh1 = (const float*)d_in[8];
    const float* b_ih1 = (const float*)d_in[9];
    const float* b_hh1 = (const float*)d_in[10];
    float* outp = (float*)d_out;
    unsigned short* wsp = (unsigned short*)d_ws;

    void* args[] = { &x, &hx, &cx, &w_ih0, &w_hh0, &b_ih0, &b_hh0,
                     &w_ih1, &w_hh1, &b_ih1, &b_hh1, &outp, &wsp };
    hipLaunchCooperativeKernel((void*)lstm_fused, dim3(256), dim3(256),
                               args, 0, stream);
}

// Round 6
// 8776.694 us; speedup vs baseline: 1.1311x; 1.1311x over previous
//
#include <hip/hip_runtime.h>
#include <hip/hip_bf16.h>
#include <hip/hip_cooperative_groups.h>
#include <cstddef>

namespace cg = cooperative_groups;

typedef short bf16x8 __attribute__((ext_vector_type(8)));
typedef float f32x4 __attribute__((ext_vector_type(4)));

#define T_STEPS 512
#define BATCH   64
#define DIM     1024   // I == H == 1024
#define BD      (BATCH*DIM)      // 65536
#define XB_ELEMS ((size_t)T_STEPS*BATCH*DIM)  // 33554432
#define FLAG_STRIDE 16           // uints -> 64B apart: spread over 128 L3 lines

__device__ __forceinline__ float sigmoidf_(float x) {
    return 1.f / (1.f + __expf(-x));
}
__device__ __forceinline__ float tanhf_(float x) {
    return 2.f / (1.f + __expf(-2.f * x)) - 1.f;
}
__device__ __forceinline__ unsigned short f2bf(float f) {
    union { float f; unsigned int u; } v; v.f = f;
    unsigned int u = v.u + 0x7fffu + ((v.u >> 16) & 1u);  // RNE
    return (unsigned short)(u >> 16);
}

// coherent (agent-scope, cache-bypassing) 8B primitives for h traffic
__device__ __forceinline__ unsigned long long coh_load8(const void* p) {
    return __hip_atomic_load((const unsigned long long*)p,
                             __ATOMIC_RELAXED, __HIP_MEMORY_SCOPE_AGENT);
}
__device__ __forceinline__ void coh_store8(void* p, unsigned long long v) {
    __hip_atomic_store((unsigned long long*)p, v,
                       __ATOMIC_RELAXED, __HIP_MEMORY_SCOPE_AGENT);
}

// Grid: 256 blocks x 256 threads. Blocks 0..127 -> layer 0, 128..255 -> layer 1.
__global__ void __launch_bounds__(256, 1)
lstm_fused(const float* __restrict__ x,
           const float* __restrict__ hx,
           const float* __restrict__ cx,
           const float* __restrict__ w_ih0, const float* __restrict__ w_hh0,
           const float* __restrict__ b_ih0, const float* __restrict__ b_hh0,
           const float* __restrict__ w_ih1, const float* __restrict__ w_hh1,
           const float* __restrict__ b_ih1, const float* __restrict__ b_hh1,
           float* __restrict__ out,
           unsigned short* __restrict__ ws)
{
    // ws layout (bf16 elems): xb[T][B][DIM], h0[4][BD], h1[2][BD], flags
    unsigned short* xb = ws;
    unsigned short* h0 = ws + XB_ELEMS;
    unsigned short* h1 = h0 + 4 * BD;
    unsigned* flag0 = (unsigned*)(h1 + 2 * BD);   // [128 * FLAG_STRIDE]
    unsigned* flag1 = flag0 + 128 * FLAG_STRIDE;  // [128 * FLAG_STRIDE]

    const int tid   = threadIdx.x;
    const int lane  = tid & 63;
    const int wave  = tid >> 6;
    const int bid   = blockIdx.x;
    const int layer = bid >> 7;
    const int ib    = bid & 127;
    const int hb    = ib * 8;          // first hidden unit owned by this block

    // B operand in MFMA fragment order: [g(2)][ntile(2)][kchunk(32)][lane(64)][8]
    __shared__ __align__(16) unsigned short wB[65536];     // 128 KB
    __shared__ __align__(16) unsigned short hstage[64][8]; // 1 KB repack tile

    // ---- stage weight slices into LDS (one-time), fragment layout ----
    {
        const float* wsrcI = layer ? w_ih1 : w_ih0;
        const float* wsrcH = layer ? w_hh1 : w_hh0;
        for (int idx = tid; idx < 8192; idx += 256) {   // 8192 fragments of 8
            int l  = idx & 63;
            int kc = (idx >> 6) & 31;
            int n  = (idx >> 11) & 1;
            int g  = idx >> 12;
            int c  = l & 15, kq = l >> 4;
            int gate = n * 2 + (c >> 3);                // 0:i 1:f 2:g 3:o
            const float* wm = g ? wsrcH : wsrcI;
            const float* src = wm + (size_t)(gate * DIM + hb + (c & 7)) * DIM + kc * 32 + kq * 8;
            float4 v0 = *(const float4*)(src);
            float4 v1 = *(const float4*)(src + 4);
            unsigned short o[8];
            o[0] = f2bf(v0.x); o[1] = f2bf(v0.y); o[2] = f2bf(v0.z); o[3] = f2bf(v0.w);
            o[4] = f2bf(v1.x); o[5] = f2bf(v1.y); o[6] = f2bf(v1.z); o[7] = f2bf(v1.w);
            *(bf16x8*)(&wB[(size_t)idx * 8]) = *(const bf16x8*)o;
        }
    }

    // ---- cast x to bf16 into ws (grid-stride) ----
    {
        const int nthr = 256 * gridDim.x;
        const int gtid = bid * 256 + tid;
        const float4* xv = (const float4*)x;
        const int n4 = (int)(XB_ELEMS / 4);
        for (int i = gtid; i < n4; i += nthr) {
            float4 v = xv[i];
            ushort4 o;
            o.x = f2bf(v.x); o.y = f2bf(v.y); o.z = f2bf(v.z); o.w = f2bf(v.w);
            *(ushort4*)(xb + (size_t)i * 4) = o;
        }
    }

    // ---- init h ring slots holding h[-1] (l0: slot 3 of 4; l1: slot 1 of 2) ----
    {
        unsigned short* hdst = layer ? (h1 + BD) : (h0 + 3 * BD);
        const float* hsrc = hx + (size_t)layer * BD;
        for (int e = tid; e < 512; e += 256) {
            int row = e >> 3, u = e & 7;
            hdst[row * DIM + hb + u] = f2bf(hsrc[row * DIM + hb + u]);
        }
    }

    // ---- zero own flag word (every launch; deterministic under graph replay) ----
    if (tid == 0) {
        unsigned* f = (layer ? flag1 : flag0) + ib * FLAG_STRIDE;
        __hip_atomic_store(f, 0u, __ATOMIC_RELAXED, __HIP_MEMORY_SCOPE_AGENT);
    }

    const int col  = lane & 15;      // MFMA col within N-tile
    const int quad = lane >> 4;      // 0..3
    const bool lo  = col < 8;
    const int u    = lane & 7;       // hidden-unit offset for lo lanes

    // biases (per-lane, constant over time)
    const float* bi = layer ? b_ih1 : b_ih0;
    const float* bh = layer ? b_hh1 : b_hh0;
    const int r0 = (col < 8) ? (0 * DIM + hb + col) : (1 * DIM + hb + col - 8); // i|f
    const int r1 = (col < 8) ? (2 * DIM + hb + col) : (3 * DIM + hb + col - 8); // g|o
    const float bias0 = bi[r0] + bh[r0];
    const float bias1 = bi[r1] + bh[r1];

    // c-state in registers (lo lanes own 4 batch rows each)
    float creg[4];
    {
        const float* csrc = cx + (size_t)layer * BD;
        #pragma unroll
        for (int r = 0; r < 4; ++r) {
            int m = wave * 16 + quad * 4 + r;
            creg[r] = lo ? csrc[m * DIM + hb + u] : 0.f;
        }
    }

    cg::grid_group grid = cg::this_grid();
    __syncthreads();
    grid.sync();   // publishes xb, h init, zeroed flags (wbl2 + inv once)

    const int arow = wave * 16 + col;  // A-fragment row (batch index)

    // plain-load GEMM (xb path: L2-cacheable, stays warm — no invalidates ever)
    auto do_gemm_plain = [&](const unsigned short* Ap, int g, f32x4& a0v, f32x4& a1v) {
        const unsigned short* Abase = Ap + (size_t)arow * DIM + quad * 8;
        const unsigned short* B0 = &wB[(size_t)((g * 2 + 0) * 32) * 512 + lane * 8];
        const unsigned short* B1 = &wB[(size_t)((g * 2 + 1) * 32) * 512 + lane * 8];
        #pragma unroll 8
        for (int kc = 0; kc < 32; ++kc) {
            bf16x8 a  = *(const bf16x8*)(Abase + kc * 32);
            bf16x8 b0 = *(const bf16x8*)(B0 + (size_t)kc * 512);
            bf16x8 b1 = *(const bf16x8*)(B1 + (size_t)kc * 512);
            a0v = __builtin_amdgcn_mfma_f32_16x16x32_bf16(a, b0, a0v, 0, 0, 0);
            a1v = __builtin_amdgcn_mfma_f32_16x16x32_bf16(a, b1, a1v, 0, 0, 0);
        }
    };

    // coherent-load GEMM, 8-deep register prefetch (16 loads in flight/lane)
    auto do_gemm_coh = [&](const unsigned short* Ap, int g, f32x4& a0v, f32x4& a1v) {
        const unsigned short* Abase = Ap + (size_t)arow * DIM + quad * 8;
        const unsigned short* B0 = &wB[(size_t)((g * 2 + 0) * 32) * 512 + lane * 8];
        const unsigned short* B1 = &wB[(size_t)((g * 2 + 1) * 32) * 512 + lane * 8];
        union U { bf16x8 v; unsigned long long q[2]; };
        U pre[8];
        #pragma unroll
        for (int i = 0; i < 8; ++i) {
            pre[i].q[0] = coh_load8(Abase + i * 32);
            pre[i].q[1] = coh_load8(Abase + i * 32 + 4);
        }
        #pragma unroll
        for (int kc = 0; kc < 32; ++kc) {
            U cur = pre[kc & 7];
            if (kc < 24) {
                pre[kc & 7].q[0] = coh_load8(Abase + (kc + 8) * 32);
                pre[kc & 7].q[1] = coh_load8(Abase + (kc + 8) * 32 + 4);
            }
            bf16x8 b0 = *(const bf16x8*)(B0 + (size_t)kc * 512);
            bf16x8 b1 = *(const bf16x8*)(B1 + (size_t)kc * 512);
            a0v = __builtin_amdgcn_mfma_f32_16x16x32_bf16(cur.v, b0, a0v, 0, 0, 0);
            a1v = __builtin_amdgcn_mfma_f32_16x16x32_bf16(cur.v, b1, a1v, 0, 0, 0);
        }
    };

    // early-probe at loop top; ONE merged wait phase per step (single barrier)
    auto probe = [&](const unsigned* flags) -> unsigned {
        return (tid < 128)
            ? __hip_atomic_load(flags + tid * FLAG_STRIDE,
                                __ATOMIC_RELAXED, __HIP_MEMORY_SCOPE_AGENT)
            : 0xFFFFFFFFu;
    };
    auto finish_wait2 = [&](const unsigned* fA, unsigned tA, unsigned sA,
                            const unsigned* fB, unsigned tB, unsigned sB) {
        if (tid < 128) {
            bool needA = (sA < tA), needB = (sB < tB);
            while (needA || needB) {
                if (needA && __hip_atomic_load(fA + tid * FLAG_STRIDE, __ATOMIC_RELAXED,
                                               __HIP_MEMORY_SCOPE_AGENT) >= tA) needA = false;
                if (needB && __hip_atomic_load(fB + tid * FLAG_STRIDE, __ATOMIC_RELAXED,
                                               __HIP_MEMORY_SCOPE_AGENT) >= tB) needB = false;
                if (needA || needB) __builtin_amdgcn_s_sleep(2);
            }
        }
        __syncthreads();
    };

    unsigned* myflag = (layer ? flag1 : flag0) + ib * FLAG_STRIDE;

    for (int t = 0; t < T_STEPS; ++t) {
        f32x4 acc0 = {0.f, 0.f, 0.f, 0.f};
        f32x4 acc1 = {0.f, 0.f, 0.f, 0.f};
        unsigned pf0 = probe(flag0);
        unsigned pf1 = probe(flag1);

        if (!layer) {
            // input GEMM on static xb[t] — covers probe + peers finishing t-1
            do_gemm_plain(xb + (size_t)t * BD, 0, acc0, acc1);
            // merged: peers' h0[t-1] ready AND ring slot t&3 free (l1 ≥ t-3)
            finish_wait2(flag0, (unsigned)t, pf0,
                         flag1, (t >= 4) ? (unsigned)(t - 3) : 0u, pf1);
            do_gemm_coh(h0 + (size_t)((t - 1) & 3) * BD, 1, acc0, acc1);
        } else {
            // merged: peers' h1[t-1] ready AND layer0's h0[t] ready (usually
            // pre-satisfied: l0 runs up to 4 steps ahead on its ring)
            finish_wait2(flag1, (unsigned)t, pf1,
                         flag0, (unsigned)(t + 1), pf0);
            do_gemm_coh(h1 + (size_t)((t - 1) & 1) * BD, 1, acc0, acc1);
            do_gemm_coh(h0 + (size_t)(t & 3) * BD, 0, acc0, acc1);
        }

        unsigned short* hout = layer ? (h1 + (size_t)(t & 1) * BD)
                                     : (h0 + (size_t)(t & 3) * BD);
        float hreg[4];
        #pragma unroll
        for (int r = 0; r < 4; ++r) {
            float pre0 = acc0[r] + bias0;          // i (lo) | f (hi)
            float pre1 = acc1[r] + bias1;          // g (lo) | o (hi)
            float alt0 = __shfl_xor(pre0, 8);
            float alt1 = __shfl_xor(pre1, 8);
            if (lo) {
                float ig = sigmoidf_(pre0);
                float fg = sigmoidf_(alt0);
                float gg = tanhf_(pre1);
                float og = sigmoidf_(alt1);
                float c  = fg * creg[r] + ig * gg;
                creg[r]  = c;
                float h  = og * tanhf_(c);
                hreg[r]  = h;
                int m = wave * 16 + quad * 4 + r;
                hstage[m][u] = f2bf(h);
            }
        }
        __syncthreads();                 // hstage complete (single barrier)
        if (tid < 64) {                  // wave 0 alone: store h + publish
            const unsigned long long* src = (const unsigned long long*)&hstage[tid][0];
            unsigned long long v0 = src[0], v1 = src[1];
            void* dst = hout + (size_t)tid * DIM + hb;
            coh_store8(dst, v0);
            coh_store8((char*)dst + 8, v1);
            asm volatile("s_waitcnt vmcnt(0)" ::: "memory");   // wave0's h at L3
            if (tid == 0)
                __hip_atomic_store(myflag, (unsigned)(t + 1),
                                   __ATOMIC_RELAXED, __HIP_MEMORY_SCOPE_AGENT);
        }

        // non-critical-path output stores (after publish)
        if (lo) {
            #pragma unroll
            for (int r = 0; r < 4; ++r) {
                int m = wave * 16 + quad * 4 + r;
                if (layer) {
                    out[(size_t)t * BD + m * DIM + hb + u] = hreg[r];
                    if (t == T_STEPS - 1) {
                        out[(size_t)T_STEPS * BD + 1 * BD + m * DIM + hb + u] = hreg[r];  // hn[1]
                        out[(size_t)T_STEPS * BD + 3 * BD + m * DIM + hb + u] = creg[r];  // cn[1]
                    }
                } else if (t == T_STEPS - 1) {
                    out[(size_t)T_STEPS * BD + 0 * BD + m * DIM + hb + u] = hreg[r];      // hn[0]
                    out[(size_t)T_STEPS * BD + 2 * BD + m * DIM + hb + u] = creg[r];      // cn[0]
                }
            }
        }
    }
}

extern "C" void kernel_launch(void* const* d_in, const int* in_sizes, int n_in,
                              void* d_out, int out_size, void* d_ws, size_t ws_size,
                              hipStream_t stream) {
    const float* x     = (const float*)d_in[0];
    const float* hx    = (const float*)d_in[1];
    const float* cx    = (const float*)d_in[2];
    const float* w_ih0 = (const float*)d_in[3];
    const float* w_hh0 = (const float*)d_in[4];
    const float* b_ih0 = (const float*)d_in[5];
    const float* b_hh0 = (const float*)d_in[6];
    const float* w_ih1 = (const float*)d_in[7];
    const float* w_hh1 = (const float*)d_in[8];
    const float* b_ih1 = (const float*)d_in[9];
    const float* b_hh1 = (const float*)d_in[10];
    float* outp = (float*)d_out;
    unsigned short* wsp = (unsigned short*)d_ws;

    void* args[] = { &x, &hx, &cx, &w_ih0, &w_hh0, &b_ih0, &b_hh0,
                     &w_ih1, &w_hh1, &b_ih1, &b_hh1, &outp, &wsp };
    hipLaunchCooperativeKernel((void*)lstm_fused, dim3(256), dim3(256),
                               args, 0, stream);
}

// Round 9
// 5750.225 us; speedup vs baseline: 1.7264x; 1.5263x over previous
//
#include <hip/hip_runtime.h>
#include <hip/hip_bf16.h>
#include <hip/hip_cooperative_groups.h>
#include <cstddef>

namespace cg = cooperative_groups;

typedef short bf16x8 __attribute__((ext_vector_type(8)));
typedef float f32x4 __attribute__((ext_vector_type(4)));

#define T_STEPS 512
#define BATCH   64
#define DIM     1024
#define BD      (BATCH*DIM)                   // 65536
#define XB_ELEMS ((size_t)T_STEPS*BATCH*DIM)  // 33554432
#define IGSLOT  262144                        // f32 per ig ring slot (64ug*4096)
#define FSTRIDE 16                            // flag stride in uints (64B)

__device__ __forceinline__ float sigmoidf_(float x) { return 1.f / (1.f + __expf(-x)); }
__device__ __forceinline__ float tanhf_(float x)    { return 2.f / (1.f + __expf(-2.f * x)) - 1.f; }
__device__ __forceinline__ unsigned short f2bf(float f) {
    union { float f; unsigned int u; } v; v.f = f;
    unsigned int u = v.u + 0x7fffu + ((v.u >> 16) & 1u);
    return (unsigned short)(u >> 16);
}

// proven coherent (agent-scope, L1/L2-bypassing) 8B primitives
__device__ __forceinline__ unsigned long long coh_load8(const void* p) {
    return __hip_atomic_load((const unsigned long long*)p,
                             __ATOMIC_RELAXED, __HIP_MEMORY_SCOPE_AGENT);
}
__device__ __forceinline__ void coh_store8(void* p, unsigned long long v) {
    __hip_atomic_store((unsigned long long*)p, v,
                       __ATOMIC_RELAXED, __HIP_MEMORY_SCOPE_AGENT);
}

// 256 blocks x 256 threads. Roles of 64 blocks (ug = unit-group, 16 units each):
// role0 l0-inp: ig0[t] = W_ih0 @ xb[t] + biases0    (cached xb reads, runs ahead)
// role1 l0-rec: h0[t]  = lstm(W_hh0 @ h0[t-1] + ig0[t])
// role2 l1-inp: ig1[t] = W_ih1 @ h0[t] + biases1    (coherent h0 reads)
// role3 l1-rec: h1[t]  = lstm(W_hh1 @ h1[t-1] + ig1[t]) -> out
__global__ void __launch_bounds__(256, 1)
lstm_fused(const float* __restrict__ x,
           const float* __restrict__ hx,
           const float* __restrict__ cx,
           const float* __restrict__ w_ih0, const float* __restrict__ w_hh0,
           const float* __restrict__ b_ih0, const float* __restrict__ b_hh0,
           const float* __restrict__ w_ih1, const float* __restrict__ w_hh1,
           const float* __restrict__ b_ih1, const float* __restrict__ b_hh1,
           float* __restrict__ out,
           unsigned short* __restrict__ ws)
{
    // ws: xb[T][B][DIM] bf16, h0 ring[4][BD] bf16, h1 ring[2][BD] bf16,
    //     ig0 ring[2][IGSLOT] f32, ig1 ring[2][IGSLOT] f32, flags[4][64*FSTRIDE]
    unsigned short* xb = ws;
    unsigned short* h0 = ws + XB_ELEMS;
    unsigned short* h1 = h0 + 4 * BD;
    float* ig0 = (float*)(h1 + 2 * BD);
    float* ig1 = ig0 + 2 * IGSLOT;
    unsigned* flags = (unsigned*)(ig1 + 2 * IGSLOT);

    const int tid  = threadIdx.x;
    const int lane = tid & 63;
    const int wave = tid >> 6;
    const int bid  = blockIdx.x;
    const int role = bid >> 6;          // 0..3
    const int ug   = bid & 63;          // unit-group: units ug*16..ug*16+15
    const int ub   = ug * 16;

    __shared__ __align__(16) unsigned short wB[65536];      // 128 KB fragment-order weights
    __shared__ __align__(16) unsigned short hstage[64][16]; // 2 KB h repack

    // ---- stage this role's weight matrix into LDS (fragment order) ----
    {
        const float* wm = (role == 0) ? w_ih0 : (role == 1) ? w_hh0
                        : (role == 2) ? w_ih1 : w_hh1;
        for (int idx = tid; idx < 8192; idx += 256) {
            int l  = idx & 63;
            int kc = (idx >> 6) & 31;
            int n  = idx >> 11;                 // gate 0..3 (i,f,g,o)
            int c  = l & 15, kq = l >> 4;
            const float* src = wm + (size_t)(n * DIM + ub + c) * DIM + kc * 32 + kq * 8;
            float4 v0 = *(const float4*)(src);
            float4 v1 = *(const float4*)(src + 4);
            unsigned short o[8];
            o[0]=f2bf(v0.x); o[1]=f2bf(v0.y); o[2]=f2bf(v0.z); o[3]=f2bf(v0.w);
            o[4]=f2bf(v1.x); o[5]=f2bf(v1.y); o[6]=f2bf(v1.z); o[7]=f2bf(v1.w);
            *(bf16x8*)(&wB[(size_t)idx * 8]) = *(const bf16x8*)o;
        }
    }

    // ---- cast x to bf16 (grid-stride, all blocks) ----
    {
        const int nthr = 256 * gridDim.x;
        const int gtid = bid * 256 + tid;
        const float4* xv = (const float4*)x;
        const int n4 = (int)(XB_ELEMS / 4);
        for (int i = gtid; i < n4; i += nthr) {
            float4 v = xv[i];
            ushort4 o;
            o.x=f2bf(v.x); o.y=f2bf(v.y); o.z=f2bf(v.z); o.w=f2bf(v.w);
            *(ushort4*)(xb + (size_t)i * 4) = o;
        }
    }

    // ---- h[-1] into ring (l0: slot 3 of 4; l1: slot 1 of 2) ----
    if (role == 1 || role == 3) {
        unsigned short* hdst = (role == 1) ? (h0 + 3 * BD) : (h1 + 1 * BD);
        const float* hsrc = hx + (size_t)(role >> 1) * BD;
        for (int e = tid; e < 1024; e += 256) {       // 64 rows x 16 units
            int row = e >> 4, uu = e & 15;
            hdst[row * DIM + ub + uu] = f2bf(hsrc[row * DIM + ub + uu]);
        }
    }

    // ---- zero own flag ----
    if (tid == 0)
        __hip_atomic_store(flags + (size_t)((role << 6) | ug) * FSTRIDE, 0u,
                           __ATOMIC_RELAXED, __HIP_MEMORY_SCOPE_AGENT);

    const int col  = lane & 15;      // unit (N) index within tile
    const int quad = lane >> 4;

    // biases for producer roles (full layer bias baked into ig)
    float biasv[4] = {0.f, 0.f, 0.f, 0.f};
    if (role == 0 || role == 2) {
        const float* bi = (role == 0) ? b_ih0 : b_ih1;
        const float* bh = (role == 0) ? b_hh0 : b_hh1;
        #pragma unroll
        for (int n = 0; n < 4; ++n) {
            int row = n * DIM + ub + col;
            biasv[n] = bi[row] + bh[row];
        }
    }

    // c-state for rec roles (all lanes active; 4 batch rows each)
    float creg[4] = {0.f, 0.f, 0.f, 0.f};
    if (role == 1 || role == 3) {
        const float* csrc = cx + (size_t)(role >> 1) * BD;
        #pragma unroll
        for (int r = 0; r < 4; ++r) {
            int m = wave * 16 + quad * 4 + r;
            creg[r] = csrc[m * DIM + ub + col];
        }
    }

    cg::grid_group grid = cg::this_grid();
    __syncthreads();
    grid.sync();   // release: xb / h-init / flag zeros visible below coherence point

    const int arow = wave * 16 + col;   // A-fragment batch row

    auto poll_ge = [&](const unsigned* f, int target) {
        while ((int)__hip_atomic_load(f, __ATOMIC_RELAXED, __HIP_MEMORY_SCOPE_AGENT) < target)
            __builtin_amdgcn_s_sleep(1);
    };
    auto Fp = [&](int set, int idx) -> unsigned* {
        return flags + (size_t)((set << 6) | idx) * FSTRIDE;
    };
    auto publish = [&](int set, int idx, int val) {
        __hip_atomic_store(Fp(set, idx), (unsigned)val,
                           __ATOMIC_RELAXED, __HIP_MEMORY_SCOPE_AGENT);
    };

    // plain-load GEMM (cached A: xb path), 4 gate N-tiles
    auto gemm_plain = [&](const unsigned short* Ap,
                          f32x4& A0, f32x4& A1, f32x4& A2, f32x4& A3) {
        const unsigned short* Abase = Ap + (size_t)arow * DIM + quad * 8;
        #pragma unroll 8
        for (int kc = 0; kc < 32; ++kc) {
            bf16x8 a  = *(const bf16x8*)(Abase + kc * 32);
            bf16x8 b0 = *(const bf16x8*)(&wB[((size_t)(0*32 + kc)*64 + lane)*8]);
            bf16x8 b1 = *(const bf16x8*)(&wB[((size_t)(1*32 + kc)*64 + lane)*8]);
            bf16x8 b2 = *(const bf16x8*)(&wB[((size_t)(2*32 + kc)*64 + lane)*8]);
            bf16x8 b3 = *(const bf16x8*)(&wB[((size_t)(3*32 + kc)*64 + lane)*8]);
            A0 = __builtin_amdgcn_mfma_f32_16x16x32_bf16(a, b0, A0, 0, 0, 0);
            A1 = __builtin_amdgcn_mfma_f32_16x16x32_bf16(a, b1, A1, 0, 0, 0);
            A2 = __builtin_amdgcn_mfma_f32_16x16x32_bf16(a, b2, A2, 0, 0, 0);
            A3 = __builtin_amdgcn_mfma_f32_16x16x32_bf16(a, b3, A3, 0, 0, 0);
        }
    };

    // coherent-A GEMM: proven 8B atomic loads, 8-deep rolling prefetch
    auto gemm_coh = [&](const unsigned short* Ap, const float* igl,
                        f32x4& A0, f32x4& A1, f32x4& A2, f32x4& A3) {
        const unsigned short* Abase = Ap + (size_t)arow * DIM + quad * 8;
        if (igl) {
            union { f32x4 v; unsigned long long q[2]; } g0, g1, g2, g3;
            g0.q[0] = coh_load8(igl + 0);  g0.q[1] = coh_load8(igl + 2);
            g1.q[0] = coh_load8(igl + 4);  g1.q[1] = coh_load8(igl + 6);
            g2.q[0] = coh_load8(igl + 8);  g2.q[1] = coh_load8(igl + 10);
            g3.q[0] = coh_load8(igl + 12); g3.q[1] = coh_load8(igl + 14);
            A0 = g0.v; A1 = g1.v; A2 = g2.v; A3 = g3.v;
        }
        union U { bf16x8 v; unsigned long long q[2]; };
        U pre[8];
        #pragma unroll
        for (int i = 0; i < 8; ++i) {
            pre[i].q[0] = coh_load8(Abase + i * 32);
            pre[i].q[1] = coh_load8(Abase + i * 32 + 4);
        }
        #pragma unroll
        for (int kc = 0; kc < 32; ++kc) {
            U cur = pre[kc & 7];
            if (kc < 24) {
                pre[kc & 7].q[0] = coh_load8(Abase + (kc + 8) * 32);
                pre[kc & 7].q[1] = coh_load8(Abase + (kc + 8) * 32 + 4);
            }
            bf16x8 b0 = *(const bf16x8*)(&wB[((size_t)(0*32 + kc)*64 + lane)*8]);
            bf16x8 b1 = *(const bf16x8*)(&wB[((size_t)(1*32 + kc)*64 + lane)*8]);
            bf16x8 b2 = *(const bf16x8*)(&wB[((size_t)(2*32 + kc)*64 + lane)*8]);
            bf16x8 b3 = *(const bf16x8*)(&wB[((size_t)(3*32 + kc)*64 + lane)*8]);
            A0 = __builtin_amdgcn_mfma_f32_16x16x32_bf16(cur.v, b0, A0, 0, 0, 0);
            A1 = __builtin_amdgcn_mfma_f32_16x16x32_bf16(cur.v, b1, A1, 0, 0, 0);
            A2 = __builtin_amdgcn_mfma_f32_16x16x32_bf16(cur.v, b2, A2, 0, 0, 0);
            A3 = __builtin_amdgcn_mfma_f32_16x16x32_bf16(cur.v, b3, A3, 0, 0, 0);
        }
    };

    // producer epilogue: dump acc (lane-contiguous 64B) + drain + publish
    auto dump_ig = [&](float* slot, int set, int t,
                       f32x4 A0, f32x4 A1, f32x4 A2, f32x4 A3) {
        float* dst = slot + (size_t)ug * 4096 + (size_t)(wave * 64 + lane) * 16;
        union { f32x4 v; unsigned long long q[2]; } u0, u1, u2, u3;
        u0.v = A0; u1.v = A1; u2.v = A2; u3.v = A3;
        coh_store8(dst + 0,  u0.q[0]); coh_store8(dst + 2,  u0.q[1]);
        coh_store8(dst + 4,  u1.q[0]); coh_store8(dst + 6,  u1.q[1]);
        coh_store8(dst + 8,  u2.q[0]); coh_store8(dst + 10, u2.q[1]);
        coh_store8(dst + 12, u3.q[0]); coh_store8(dst + 14, u3.q[1]);
        asm volatile("s_waitcnt vmcnt(0)" ::: "memory");
        __syncthreads();
        if (tid == 0) publish(set, ug, t + 1);
    };

    for (int t = 0; t < T_STEPS; ++t) {
        f32x4 A0, A1, A2, A3;

        if (role == 0) {            // ---------- l0-inp ----------
            if (tid == 0) poll_ge(Fp(1, ug), t - 1);          // ig0 slot t&1 free
            __syncthreads();
            A0 = f32x4{biasv[0], biasv[0], biasv[0], biasv[0]};
            A1 = f32x4{biasv[1], biasv[1], biasv[1], biasv[1]};
            A2 = f32x4{biasv[2], biasv[2], biasv[2], biasv[2]};
            A3 = f32x4{biasv[3], biasv[3], biasv[3], biasv[3]};
            gemm_plain(xb + (size_t)t * BD, A0, A1, A2, A3);
            dump_ig(ig0 + (size_t)(t & 1) * IGSLOT, 0, t, A0, A1, A2, A3);

        } else if (role == 2) {     // ---------- l1-inp ----------
            if (tid < 64) poll_ge(Fp(1, tid), t + 1);         // h0[t] ready (all)
            else if (tid == 64) poll_ge(Fp(3, ug), t - 1);    // ig1 slot t&1 free
            __syncthreads();
            A0 = f32x4{biasv[0], biasv[0], biasv[0], biasv[0]};
            A1 = f32x4{biasv[1], biasv[1], biasv[1], biasv[1]};
            A2 = f32x4{biasv[2], biasv[2], biasv[2], biasv[2]};
            A3 = f32x4{biasv[3], biasv[3], biasv[3], biasv[3]};
            gemm_coh(h0 + (size_t)(t & 3) * BD, nullptr, A0, A1, A2, A3);
            dump_ig(ig1 + (size_t)(t & 1) * IGSLOT, 2, t, A0, A1, A2, A3);

        } else {                    // ---------- rec roles ----------
            if (role == 1) {
                if (tid < 64) poll_ge(Fp(1, tid), t);                 // peers' h0[t-1]
                else if (tid < 128) poll_ge(Fp(2, tid - 64), t - 3);  // h0 slot t&3 free
                else if (tid == 128) poll_ge(Fp(0, ug), t + 1);       // ig0[t] ready
            } else {
                if (tid < 64) poll_ge(Fp(3, tid), t);                 // peers' h1[t-1]
                else if (tid == 64) poll_ge(Fp(2, ug), t + 1);        // ig1[t] ready
            }
            __syncthreads();

            unsigned short* hring = (role == 1) ? h0 : h1;
            const unsigned short* hsrc = (role == 1)
                ? (h0 + (size_t)((t - 1) & 3) * BD)
                : (h1 + (size_t)((t - 1) & 1) * BD);
            const float* igp = ((role == 1) ? ig0 : ig1) + (size_t)(t & 1) * IGSLOT
                             + (size_t)ug * 4096 + (size_t)(wave * 64 + lane) * 16;
            gemm_coh(hsrc, igp, A0, A1, A2, A3);

            float hreg[4];
            #pragma unroll
            for (int r = 0; r < 4; ++r) {
                float ig_ = sigmoidf_(A0[r]);
                float fg_ = sigmoidf_(A1[r]);
                float gg_ = tanhf_(A2[r]);
                float og_ = sigmoidf_(A3[r]);
                float c   = fg_ * creg[r] + ig_ * gg_;
                creg[r]   = c;
                float h   = og_ * tanhf_(c);
                hreg[r]   = h;
                int m = wave * 16 + quad * 4 + r;
                hstage[m][col] = f2bf(h);
            }
            __syncthreads();                        // hstage complete
            unsigned short* hout = hring
                + (size_t)((role == 1) ? (t & 3) : (t & 1)) * BD;
            if (wave == 0) {                        // 32B/lane contiguous
                const unsigned long long* src = (const unsigned long long*)&hstage[lane][0];
                unsigned long long v0 = src[0], v1 = src[1], v2 = src[2], v3 = src[3];
                unsigned short* dst = hout + (size_t)lane * DIM + ub;
                coh_store8(dst + 0,  v0);
                coh_store8(dst + 4,  v1);
                coh_store8(dst + 8,  v2);
                coh_store8(dst + 12, v3);
                asm volatile("s_waitcnt vmcnt(0)" ::: "memory");  // wave-level drain
                if (tid == 0) publish(role, ug, t + 1);
            }

            // off-critical-path output stores
            if (role == 3) {
                #pragma unroll
                for (int r = 0; r < 4; ++r) {
                    int m = wave * 16 + quad * 4 + r;
                    out[(size_t)t * BD + (size_t)m * DIM + ub + col] = hreg[r];
                    if (t == T_STEPS - 1) {
                        out[(size_t)T_STEPS * BD + 1 * BD + m * DIM + ub + col] = hreg[r];
                        out[(size_t)T_STEPS * BD + 3 * BD + m * DIM + ub + col] = creg[r];
                    }
                }
            } else if (t == T_STEPS - 1) {
                #pragma unroll
                for (int r = 0; r < 4; ++r) {
                    int m = wave * 16 + quad * 4 + r;
                    out[(size_t)T_STEPS * BD + 0 * BD + m * DIM + ub + col] = hreg[r];
                    out[(size_t)T_STEPS * BD + 2 * BD + m * DIM + ub + col] = creg[r];
                }
            }
        }
    }
}

extern "C" void kernel_launch(void* const* d_in, const int* in_sizes, int n_in,
                              void* d_out, int out_size, void* d_ws, size_t ws_size,
                              hipStream_t stream) {
    const float* x     = (const float*)d_in[0];
    const float* hx    = (const float*)d_in[1];
    const float* cx    = (const float*)d_in[2];
    const float* w_ih0 = (const float*)d_in[3];
    const float* w_hh0 = (const float*)d_in[4];
    const float* b_ih0 = (const float*)d_in[5];
    const float* b_hh0 = (const float*)d_in[6];
    const float* w_ih1 = (const float*)d_in[7];
    const float* w_hh1 = (const float*)d_in[8];
    const float* b_ih1 = (const float*)d_in[9];
    const float* b_hh1 = (const float*)d_in[10];
    float* outp = (float*)d_out;
    unsigned short* wsp = (unsigned short*)d_ws;

    void* args[] = { &x, &hx, &cx, &w_ih0, &w_hh0, &b_ih0, &b_hh0,
                     &w_ih1, &w_hh1, &b_ih1, &b_hh1, &outp, &wsp };
    hipLaunchCooperativeKernel((void*)lstm_fused, dim3(256), dim3(256),
                               args, 0, stream);
}

// Round 11
// 5272.396 us; speedup vs baseline: 1.8829x; 1.0906x over previous
//
#include <hip/hip_runtime.h>
#include <hip/hip_bf16.h>
#include <hip/hip_cooperative_groups.h>
#include <cstddef>

namespace cg = cooperative_groups;

typedef short bf16x8 __attribute__((ext_vector_type(8)));
typedef float f32x4 __attribute__((ext_vector_type(4)));

#define T_STEPS 512
#define BATCH   64
#define DIM     1024
#define BD      (BATCH*DIM)                   // 65536
#define XB_ELEMS ((size_t)T_STEPS*BATCH*DIM)  // 33554432
#define IGSLOT  262144                        // f32 per ig ring slot (64ug*4096)
#define FSTRIDE 16                            // flag stride in uints (64B)

__device__ __forceinline__ float sigmoidf_(float x) { return 1.f / (1.f + __expf(-x)); }
__device__ __forceinline__ float tanhf_(float x)    { return 2.f / (1.f + __expf(-2.f * x)) - 1.f; }
__device__ __forceinline__ unsigned short f2bf(float f) {
    union { float f; unsigned int u; } v; v.f = f;
    unsigned int u = v.u + 0x7fffu + ((v.u >> 16) & 1u);
    return (unsigned short)(u >> 16);
}

// proven coherent (agent-scope, L1/L2-bypassing) 8B primitives
__device__ __forceinline__ unsigned long long coh_load8(const void* p) {
    return __hip_atomic_load((const unsigned long long*)p,
                             __ATOMIC_RELAXED, __HIP_MEMORY_SCOPE_AGENT);
}
__device__ __forceinline__ void coh_store8(void* p, unsigned long long v) {
    __hip_atomic_store((unsigned long long*)p, v,
                       __ATOMIC_RELAXED, __HIP_MEMORY_SCOPE_AGENT);
}

// 256 blocks x 256 threads. Roles of 64 blocks (ug = unit-group, 16 units each):
// role0 l0-inp: ig0[t] = W_ih0 @ xb[t] + biases0    (cached xb reads, runs ahead)
// role1 l0-rec: h0[t]  = lstm(W_hh0 @ h0[t-1] + ig0[t])
// role2 l1-inp: ig1[t] = W_ih1 @ h0[t] + biases1    (coherent h0 reads)
// role3 l1-rec: h1[t]  = lstm(W_hh1 @ h1[t-1] + ig1[t]) -> out
__global__ void __launch_bounds__(256, 1)
lstm_fused(const float* __restrict__ x,
           const float* __restrict__ hx,
           const float* __restrict__ cx,
           const float* __restrict__ w_ih0, const float* __restrict__ w_hh0,
           const float* __restrict__ b_ih0, const float* __restrict__ b_hh0,
           const float* __restrict__ w_ih1, const float* __restrict__ w_hh1,
           const float* __restrict__ b_ih1, const float* __restrict__ b_hh1,
           float* __restrict__ out,
           unsigned short* __restrict__ ws)
{
    // ws: xb[T][B][DIM] bf16, h0 ring[4][BD] bf16, h1 ring[2][BD] bf16,
    //     ig0 ring[2][IGSLOT] f32, ig1 ring[2][IGSLOT] f32, flags[4][64*FSTRIDE]
    unsigned short* xb = ws;
    unsigned short* h0 = ws + XB_ELEMS;
    unsigned short* h1 = h0 + 4 * BD;
    float* ig0 = (float*)(h1 + 2 * BD);
    float* ig1 = ig0 + 2 * IGSLOT;
    unsigned* flags = (unsigned*)(ig1 + 2 * IGSLOT);

    const int tid  = threadIdx.x;
    const int lane = tid & 63;
    const int wave = tid >> 6;
    const int bid  = blockIdx.x;
    const int role = bid >> 6;          // 0..3
    const int ug   = bid & 63;          // unit-group: units ug*16..ug*16+15
    const int ub   = ug * 16;

    __shared__ __align__(16) unsigned short wB[65536];      // 128 KB fragment-order weights
    __shared__ __align__(16) unsigned short hstage[64][16]; // 2 KB h repack

    // ---- stage this role's weight matrix into LDS (fragment order) ----
    {
        const float* wm = (role == 0) ? w_ih0 : (role == 1) ? w_hh0
                        : (role == 2) ? w_ih1 : w_hh1;
        for (int idx = tid; idx < 8192; idx += 256) {
            int l  = idx & 63;
            int kc = (idx >> 6) & 31;
            int n  = idx >> 11;                 // gate 0..3 (i,f,g,o)
            int c  = l & 15, kq = l >> 4;
            const float* src = wm + (size_t)(n * DIM + ub + c) * DIM + kc * 32 + kq * 8;
            float4 v0 = *(const float4*)(src);
            float4 v1 = *(const float4*)(src + 4);
            unsigned short o[8];
            o[0]=f2bf(v0.x); o[1]=f2bf(v0.y); o[2]=f2bf(v0.z); o[3]=f2bf(v0.w);
            o[4]=f2bf(v1.x); o[5]=f2bf(v1.y); o[6]=f2bf(v1.z); o[7]=f2bf(v1.w);
            *(bf16x8*)(&wB[(size_t)idx * 8]) = *(const bf16x8*)o;
        }
    }

    // ---- cast x to bf16 (grid-stride, all blocks) ----
    {
        const int nthr = 256 * gridDim.x;
        const int gtid = bid * 256 + tid;
        const float4* xv = (const float4*)x;
        const int n4 = (int)(XB_ELEMS / 4);
        for (int i = gtid; i < n4; i += nthr) {
            float4 v = xv[i];
            ushort4 o;
            o.x=f2bf(v.x); o.y=f2bf(v.y); o.z=f2bf(v.z); o.w=f2bf(v.w);
            *(ushort4*)(xb + (size_t)i * 4) = o;
        }
    }

    // ---- h[-1] into ring (l0: slot 3 of 4; l1: slot 1 of 2) ----
    if (role == 1 || role == 3) {
        unsigned short* hdst = (role == 1) ? (h0 + 3 * BD) : (h1 + 1 * BD);
        const float* hsrc = hx + (size_t)(role >> 1) * BD;
        for (int e = tid; e < 1024; e += 256) {       // 64 rows x 16 units
            int row = e >> 4, uu = e & 15;
            hdst[row * DIM + ub + uu] = f2bf(hsrc[row * DIM + ub + uu]);
        }
    }

    // ---- zero own flag ----
    if (tid == 0)
        __hip_atomic_store(flags + (size_t)((role << 6) | ug) * FSTRIDE, 0u,
                           __ATOMIC_RELAXED, __HIP_MEMORY_SCOPE_AGENT);

    const int col  = lane & 15;      // unit (N) index within tile
    const int quad = lane >> 4;

    // biases for producer roles (full layer bias baked into ig)
    float biasv[4] = {0.f, 0.f, 0.f, 0.f};
    if (role == 0 || role == 2) {
        const float* bi = (role == 0) ? b_ih0 : b_ih1;
        const float* bh = (role == 0) ? b_hh0 : b_hh1;
        #pragma unroll
        for (int n = 0; n < 4; ++n) {
            int row = n * DIM + ub + col;
            biasv[n] = bi[row] + bh[row];
        }
    }

    // c-state for rec roles (all lanes active; 4 batch rows each)
    float creg[4] = {0.f, 0.f, 0.f, 0.f};
    if (role == 1 || role == 3) {
        const float* csrc = cx + (size_t)(role >> 1) * BD;
        #pragma unroll
        for (int r = 0; r < 4; ++r) {
            int m = wave * 16 + quad * 4 + r;
            creg[r] = csrc[m * DIM + ub + col];
        }
    }

    cg::grid_group grid = cg::this_grid();
    __syncthreads();
    grid.sync();   // release: xb / h-init / flag zeros visible below coherence point

    const int arow = wave * 16 + col;   // A-fragment batch row

    auto poll_ge = [&](const unsigned* f, int target) {
        while ((int)__hip_atomic_load(f, __ATOMIC_RELAXED, __HIP_MEMORY_SCOPE_AGENT) < target)
            __builtin_amdgcn_s_sleep(1);
    };
    auto Fp = [&](int set, int idx) -> unsigned* {
        return flags + (size_t)((set << 6) | idx) * FSTRIDE;
    };
    auto publish = [&](int set, int idx, int val) {
        __hip_atomic_store(Fp(set, idx), (unsigned)val,
                           __ATOMIC_RELAXED, __HIP_MEMORY_SCOPE_AGENT);
    };

    // plain-load GEMM (cached A: xb path), 4 gate N-tiles
    auto gemm_plain = [&](const unsigned short* Ap,
                          f32x4& A0, f32x4& A1, f32x4& A2, f32x4& A3) {
        const unsigned short* Abase = Ap + (size_t)arow * DIM + quad * 8;
        #pragma unroll 8
        for (int kc = 0; kc < 32; ++kc) {
            bf16x8 a  = *(const bf16x8*)(Abase + kc * 32);
            bf16x8 b0 = *(const bf16x8*)(&wB[((size_t)(0*32 + kc)*64 + lane)*8]);
            bf16x8 b1 = *(const bf16x8*)(&wB[((size_t)(1*32 + kc)*64 + lane)*8]);
            bf16x8 b2 = *(const bf16x8*)(&wB[((size_t)(2*32 + kc)*64 + lane)*8]);
            bf16x8 b3 = *(const bf16x8*)(&wB[((size_t)(3*32 + kc)*64 + lane)*8]);
            A0 = __builtin_amdgcn_mfma_f32_16x16x32_bf16(a, b0, A0, 0, 0, 0);
            A1 = __builtin_amdgcn_mfma_f32_16x16x32_bf16(a, b1, A1, 0, 0, 0);
            A2 = __builtin_amdgcn_mfma_f32_16x16x32_bf16(a, b2, A2, 0, 0, 0);
            A3 = __builtin_amdgcn_mfma_f32_16x16x32_bf16(a, b3, A3, 0, 0, 0);
        }
    };

    // coherent-A GEMM: proven 8B atomic loads, 8-deep rolling prefetch.
    // ig reads use the wave-contiguous transposed layout (igb + q*128 floats).
    auto gemm_coh = [&](const unsigned short* Ap, const float* igb,
                        f32x4& A0, f32x4& A1, f32x4& A2, f32x4& A3) {
        const unsigned short* Abase = Ap + (size_t)arow * DIM + quad * 8;
        if (igb) {
            union { f32x4 v; unsigned long long q[2]; } g0, g1, g2, g3;
            g0.q[0] = coh_load8(igb + 0*128); g0.q[1] = coh_load8(igb + 1*128);
            g1.q[0] = coh_load8(igb + 2*128); g1.q[1] = coh_load8(igb + 3*128);
            g2.q[0] = coh_load8(igb + 4*128); g2.q[1] = coh_load8(igb + 5*128);
            g3.q[0] = coh_load8(igb + 6*128); g3.q[1] = coh_load8(igb + 7*128);
            A0 = g0.v; A1 = g1.v; A2 = g2.v; A3 = g3.v;
        }
        union U { bf16x8 v; unsigned long long q[2]; };
        U pre[8];
        #pragma unroll
        for (int i = 0; i < 8; ++i) {
            pre[i].q[0] = coh_load8(Abase + i * 32);
            pre[i].q[1] = coh_load8(Abase + i * 32 + 4);
        }
        #pragma unroll
        for (int kc = 0; kc < 32; ++kc) {
            U cur = pre[kc & 7];
            if (kc < 24) {
                pre[kc & 7].q[0] = coh_load8(Abase + (kc + 8) * 32);
                pre[kc & 7].q[1] = coh_load8(Abase + (kc + 8) * 32 + 4);
            }
            bf16x8 b0 = *(const bf16x8*)(&wB[((size_t)(0*32 + kc)*64 + lane)*8]);
            bf16x8 b1 = *(const bf16x8*)(&wB[((size_t)(1*32 + kc)*64 + lane)*8]);
            bf16x8 b2 = *(const bf16x8*)(&wB[((size_t)(2*32 + kc)*64 + lane)*8]);
            bf16x8 b3 = *(const bf16x8*)(&wB[((size_t)(3*32 + kc)*64 + lane)*8]);
            A0 = __builtin_amdgcn_mfma_f32_16x16x32_bf16(cur.v, b0, A0, 0, 0, 0);
            A1 = __builtin_amdgcn_mfma_f32_16x16x32_bf16(cur.v, b1, A1, 0, 0, 0);
            A2 = __builtin_amdgcn_mfma_f32_16x16x32_bf16(cur.v, b2, A2, 0, 0, 0);
            A3 = __builtin_amdgcn_mfma_f32_16x16x32_bf16(cur.v, b3, A3, 0, 0, 0);
        }
    };

    // producer epilogue: wave-contiguous q-word layout [ug][wave][q(8)][lane]
    // -> each store instruction covers a contiguous 512B (no line amplification)
    auto dump_ig = [&](float* slot, int set, int t,
                       f32x4 A0, f32x4 A1, f32x4 A2, f32x4 A3) {
        float* base = slot + (size_t)ug * 4096 + (size_t)wave * 1024 + lane * 2;
        union { f32x4 v; unsigned long long q[2]; } u0, u1, u2, u3;
        u0.v = A0; u1.v = A1; u2.v = A2; u3.v = A3;
        coh_store8(base + 0*128, u0.q[0]); coh_store8(base + 1*128, u0.q[1]);
        coh_store8(base + 2*128, u1.q[0]); coh_store8(base + 3*128, u1.q[1]);
        coh_store8(base + 4*128, u2.q[0]); coh_store8(base + 5*128, u2.q[1]);
        coh_store8(base + 6*128, u3.q[0]); coh_store8(base + 7*128, u3.q[1]);
        asm volatile("s_waitcnt vmcnt(0)" ::: "memory");
        __syncthreads();
        if (tid == 0) publish(set, ug, t + 1);
    };

    for (int t = 0; t < T_STEPS; ++t) {
        f32x4 A0, A1, A2, A3;

        if (role == 0) {            // ---------- l0-inp ----------
            if (tid == 0) poll_ge(Fp(1, ug), t - 1);          // ig0 slot t&1 free
            __syncthreads();
            A0 = f32x4{biasv[0], biasv[0], biasv[0], biasv[0]};
            A1 = f32x4{biasv[1], biasv[1], biasv[1], biasv[1]};
            A2 = f32x4{biasv[2], biasv[2], biasv[2], biasv[2]};
            A3 = f32x4{biasv[3], biasv[3], biasv[3], biasv[3]};
            gemm_plain(xb + (size_t)t * BD, A0, A1, A2, A3);
            dump_ig(ig0 + (size_t)(t & 1) * IGSLOT, 0, t, A0, A1, A2, A3);

        } else if (role == 2) {     // ---------- l1-inp ----------
            if (tid < 64) poll_ge(Fp(1, tid), t + 1);         // h0[t] ready (all)
            else if (tid == 64) poll_ge(Fp(3, ug), t - 1);    // ig1 slot t&1 free
            __syncthreads();
            A0 = f32x4{biasv[0], biasv[0], biasv[0], biasv[0]};
            A1 = f32x4{biasv[1], biasv[1], biasv[1], biasv[1]};
            A2 = f32x4{biasv[2], biasv[2], biasv[2], biasv[2]};
            A3 = f32x4{biasv[3], biasv[3], biasv[3], biasv[3]};
            gemm_coh(h0 + (size_t)(t & 3) * BD, nullptr, A0, A1, A2, A3);
            dump_ig(ig1 + (size_t)(t & 1) * IGSLOT, 2, t, A0, A1, A2, A3);

        } else {                    // ---------- rec roles ----------
            if (role == 1) {
                if (tid < 64) poll_ge(Fp(1, tid), t);                 // peers' h0[t-1]
                else if (tid < 128) poll_ge(Fp(2, tid - 64), t - 3);  // h0 slot t&3 free
                else if (tid == 128) poll_ge(Fp(0, ug), t + 1);       // ig0[t] ready
            } else {
                if (tid < 64) poll_ge(Fp(3, tid), t);                 // peers' h1[t-1]
                else if (tid == 64) poll_ge(Fp(2, ug), t + 1);        // ig1[t] ready
            }
            __syncthreads();

            unsigned short* hring = (role == 1) ? h0 : h1;
            const unsigned short* hsrc = (role == 1)
                ? (h0 + (size_t)((t - 1) & 3) * BD)
                : (h1 + (size_t)((t - 1) & 1) * BD);
            const float* igb = ((role == 1) ? ig0 : ig1) + (size_t)(t & 1) * IGSLOT
                             + (size_t)ug * 4096 + (size_t)wave * 1024 + lane * 2;
            gemm_coh(hsrc, igb, A0, A1, A2, A3);

            float hreg[4];
            #pragma unroll
            for (int r = 0; r < 4; ++r) {
                float ig_ = sigmoidf_(A0[r]);
                float fg_ = sigmoidf_(A1[r]);
                float gg_ = tanhf_(A2[r]);
                float og_ = sigmoidf_(A3[r]);
                float c   = fg_ * creg[r] + ig_ * gg_;
                creg[r]   = c;
                float h   = og_ * tanhf_(c);
                hreg[r]   = h;
                int m = wave * 16 + quad * 4 + r;
                hstage[m][col] = f2bf(h);
            }
            __syncthreads();                        // hstage complete
            unsigned short* hout = hring
                + (size_t)((role == 1) ? (t & 3) : (t & 1)) * BD;
            if (wave == 0) {                        // 32B/lane contiguous
                const unsigned long long* src = (const unsigned long long*)&hstage[lane][0];
                unsigned long long v0 = src[0], v1 = src[1], v2 = src[2], v3 = src[3];
                unsigned short* dst = hout + (size_t)lane * DIM + ub;
                coh_store8(dst + 0,  v0);
                coh_store8(dst + 4,  v1);
                coh_store8(dst + 8,  v2);
                coh_store8(dst + 12, v3);
                asm volatile("s_waitcnt vmcnt(0)" ::: "memory");  // wave-level drain
                if (tid == 0) publish(role, ug, t + 1);
            }

            // off-critical-path output stores
            if (role == 3) {
                #pragma unroll
                for (int r = 0; r < 4; ++r) {
                    int m = wave * 16 + quad * 4 + r;
                    out[(size_t)t * BD + (size_t)m * DIM + ub + col] = hreg[r];
                    if (t == T_STEPS - 1) {
                        out[(size_t)T_STEPS * BD + 1 * BD + m * DIM + ub + col] = hreg[r];
                        out[(size_t)T_STEPS * BD + 3 * BD + m * DIM + ub + col] = creg[r];
                    }
                }
            } else if (t == T_STEPS - 1) {
                #pragma unroll
                for (int r = 0; r < 4; ++r) {
                    int m = wave * 16 + quad * 4 + r;
                    out[(size_t)T_STEPS * BD + 0 * BD + m * DIM + ub + col] = hreg[r];
                    out[(size_t)T_STEPS * BD + 2 * BD + m * DIM + ub + col] = creg[r];
                }
            }
        }
    }
}

extern "C" void kernel_launch(void* const* d_in, const int* in_sizes, int n_in,
                              void* d_out, int out_size, void* d_ws, size_t ws_size,
                              hipStream_t stream) {
    const float* x     = (const float*)d_in[0];
    const float* hx    = (const float*)d_in[1];
    const float* cx    = (const float*)d_in[2];
    const float* w_ih0 = (const float*)d_in[3];
    const float* w_hh0 = (const float*)d_in[4];
    const float* b_ih0 = (const float*)d_in[5];
    const float* b_hh0 = (const float*)d_in[6];
    const float* w_ih1 = (const float*)d_in[7];
    const float* w_hh1 = (const float*)d_in[8];
    const float* b_ih1 = (const float*)d_in[9];
    const float* b_hh1 = (const float*)d_in[10];
    float* outp = (float*)d_out;
    unsigned short* wsp = (unsigned short*)d_ws;

    void* args[] = { &x, &hx, &cx, &w_ih0, &w_hh0, &b_ih0, &b_hh0,
                     &w_ih1, &w_hh1, &b_ih1, &b_hh1, &outp, &wsp };
    hipLaunchCooperativeKernel((void*)lstm_fused, dim3(256), dim3(256),
                               args, 0, stream);
}